// Round 9
// baseline (13.406 us; speedup 1.0000x reference)
//
#include <hip/hip_runtime.h>

#define NODE 512
#define DIM 64
#define BATCH 4

typedef __attribute__((ext_vector_type(8))) short bf16x8;   // 8 bf16 = 4 VGPRs
typedef __attribute__((ext_vector_type(4))) float f32x4;

#define LSTRIDE 520   // ushorts/row: 1040B = 65*16B -> ds_read_b128-aligned

__device__ __forceinline__ unsigned short f2bf(float f) {   // RNE float->bf16
    unsigned int u = __float_as_uint(f);
    u += 0x7FFF + ((u >> 16) & 1);
    return (unsigned short)(u >> 16);
}

// Grid 256 x 512thr = 1 block/CU (R6's best geometry). Block = (b, it16, dt2):
// 16 output rows x 32 channels. Cold-traffic-minimizing layout (harness fills
// flush L2/L3 between replays, so inputs are HBM-cold every replay):
//  - XCD partition: blk&7 -> it-range, so each XCD's L2 touches only 64 adj
//    rows (128KB); adj cold ~8MB -> 1MB. (blk%8->XCD round-robin heuristic;
//    wrong mapping only costs speed, not correctness.)
//  - 32-wide d: phase-1 x loads are 8 lanes x float4 = full 128B lines, no
//    line overfetch; adj shared by 2 d-tiles in-block (halves adj readers).
// Entry: prefetch wave's adj int4s (latency hides under phase 1).
// Phase 1: feat (512j x 32d) to LDS; all 8 float4 x-loads issued up front.
//   f=softplus(x*(w0/sqrt2)+b0), E=exp(f*wa+ba), W=E*f (|s|<~35: fp32-safe;
//   exact softmax ratio -- masked terms are exp(-1e9)=0).
// Phase 2: masked GEMM. Wave w owns K=64 (j in [w*64,(w+1)*64)), computes both
//   16x16 d-tiles: A-frag = adj 1/0 bf16 (shared), B via ds_read_b128, 8 MFMAs.
//   8-way LDS reduce; waves 0-1 divide + store.
// A/B frags share slot->k map (kg*8+t) so HW k-permutation cancels.
// C/D map col=lane&15, row=(lane>>4)*4+reg (verified R3-R7).
__global__ __launch_bounds__(512) void k_fused5(const float* __restrict__ x,
                                                const float* __restrict__ w0,
                                                const float* __restrict__ b0,
                                                const float* __restrict__ wa,
                                                const float* __restrict__ ba,
                                                const int* __restrict__ adj,
                                                float* __restrict__ out) {
    __shared__ unsigned short Ep[32][LSTRIDE];   // 32.5 KiB
    __shared__ unsigned short Wp[32][LSTRIDE];   // 32.5 KiB
    __shared__ f32x4 red[8][2][2][64];           // 32 KiB (kq, dtl, {D,N}, lane)

    const int blk  = blockIdx.x;                 // 256 = 8xcd * 4itl * 2dt2 * 4b
    const int xcd  = blk & 7;
    const int rest = blk >> 3;
    const int it   = xcd * 4 + (rest & 3);       // adj rows partitioned per XCD
    const int dt2  = (rest >> 2) & 1;
    const int b    = rest >> 3;
    const int i0   = it * 16;
    const int d0   = dt2 * 32;

    const int tid  = threadIdx.x;
    const int lane = tid & 63;
    const int w    = tid >> 6;       // K-chunk of 64 j
    const int fr   = lane & 15;
    const int kg   = lane >> 4;

    // ---- adj prefetch (flies during phase 1) ----
    const int* pAdj = adj + (i0 + fr) * NODE + w * 64 + kg * 8;
    int4 pa0[2], pa1[2];
    #pragma unroll
    for (int m = 0; m < 2; ++m) {
        pa0[m] = *(const int4*)(pAdj + m * 32);
        pa1[m] = *(const int4*)(pAdj + m * 32 + 4);
    }

    // ---- Phase 1: issue all x loads first (128B-line coalesced), then math ----
    float4 xv0[4], xv1[4];
    #pragma unroll
    for (int iter = 0; iter < 4; ++iter) {
        const int task = iter * 512 + tid;       // 2048 = 256jp x 8dg
        const int dg = task & 7;
        const int jp = task >> 3;
        const float* px = x + ((size_t)(b * NODE + 2 * jp) * DIM) + d0 + dg * 4;
        xv0[iter] = *(const float4*)px;
        xv1[iter] = *(const float4*)(px + DIM);
    }
    {
        const float c  = 0.7071067811865476f * w0[0];
        const float bb = b0[0];
        #pragma unroll
        for (int iter = 0; iter < 4; ++iter) {
            const int task = iter * 512 + tid;
            const int dg = task & 7;
            const int jp = task >> 3;
            #pragma unroll
            for (int i = 0; i < 4; ++i) {
                const int dl = dg * 4 + i;
                const float a0 = (i == 0) ? xv0[iter].x : (i == 1) ? xv0[iter].y
                               : (i == 2) ? xv0[iter].z : xv0[iter].w;
                const float a1 = (i == 0) ? xv1[iter].x : (i == 1) ? xv1[iter].y
                               : (i == 2) ? xv1[iter].z : xv1[iter].w;
                const float wad = wa[d0 + dl], bad = ba[d0 + dl];
                float z0 = fmaf(a0, c, bb), z1 = fmaf(a1, c, bb);
                float f0 = fmaxf(z0, 0.f) + __logf(1.f + __expf(-fabsf(z0)));
                float f1 = fmaxf(z1, 0.f) + __logf(1.f + __expf(-fabsf(z1)));
                float e0 = __expf(fmaf(f0, wad, bad));
                float e1 = __expf(fmaf(f1, wad, bad));
                unsigned int epk = (unsigned int)f2bf(e0) | ((unsigned int)f2bf(e1) << 16);
                unsigned int wpk = (unsigned int)f2bf(e0 * f0) | ((unsigned int)f2bf(e1 * f1) << 16);
                *(unsigned int*)&Ep[dl][2 * jp] = epk;
                *(unsigned int*)&Wp[dl][2 * jp] = wpk;
            }
        }
    }
    __syncthreads();

    // ---- Phase 2: masked GEMM, K=64 per wave, both d-tiles ----
    f32x4 accD[2] = {{0.f,0.f,0.f,0.f}, {0.f,0.f,0.f,0.f}};
    f32x4 accN[2] = {{0.f,0.f,0.f,0.f}, {0.f,0.f,0.f,0.f}};
    #pragma unroll
    for (int m = 0; m < 2; ++m) {
        union { bf16x8 v; unsigned short s[8]; } A;
        A.s[0] = pa0[m].x ? 0x3F80 : 0;  A.s[1] = pa0[m].y ? 0x3F80 : 0;
        A.s[2] = pa0[m].z ? 0x3F80 : 0;  A.s[3] = pa0[m].w ? 0x3F80 : 0;
        A.s[4] = pa1[m].x ? 0x3F80 : 0;  A.s[5] = pa1[m].y ? 0x3F80 : 0;
        A.s[6] = pa1[m].z ? 0x3F80 : 0;  A.s[7] = pa1[m].w ? 0x3F80 : 0;
        const int jb = w * 64 + m * 32 + kg * 8;
        #pragma unroll
        for (int dtl = 0; dtl < 2; ++dtl) {
            bf16x8 BD = *(const bf16x8*)&Ep[dtl * 16 + fr][jb];
            bf16x8 BN = *(const bf16x8*)&Wp[dtl * 16 + fr][jb];
            accD[dtl] = __builtin_amdgcn_mfma_f32_16x16x32_bf16(A.v, BD, accD[dtl], 0, 0, 0);
            accN[dtl] = __builtin_amdgcn_mfma_f32_16x16x32_bf16(A.v, BN, accN[dtl], 0, 0, 0);
        }
    }

    #pragma unroll
    for (int dtl = 0; dtl < 2; ++dtl) {
        red[w][dtl][0][lane] = accD[dtl];
        red[w][dtl][1][lane] = accN[dtl];
    }
    __syncthreads();

    if (w < 2) {
        const int dtl = w;
        f32x4 D = red[0][dtl][0][lane];
        f32x4 N = red[0][dtl][1][lane];
        #pragma unroll
        for (int q = 1; q < 8; ++q) {
            D += red[q][dtl][0][lane];
            N += red[q][dtl][1][lane];
        }
        #pragma unroll
        for (int r = 0; r < 4; ++r) {
            float dd = D[r], nn = N[r];
            float o = (dd != 0.f) ? nn / dd : 0.f;   // all-zero adj rows: P~2^-512
            out[((b * NODE) + i0 + kg * 4 + r) * DIM + d0 + dtl * 16 + fr] = o;
        }
    }
}

extern "C" void kernel_launch(void* const* d_in, const int* in_sizes, int n_in,
                              void* d_out, int out_size, void* d_ws, size_t ws_size,
                              hipStream_t stream) {
    const float* x  = (const float*)d_in[0];
    const float* w0 = (const float*)d_in[1];
    const float* b0 = (const float*)d_in[2];
    const float* wa = (const float*)d_in[3];
    const float* ba = (const float*)d_in[4];
    const int*  adj = (const int*)d_in[5];
    float* out = (float*)d_out;

    k_fused5<<<dim3(256), dim3(512), 0, stream>>>(x, w0, b0, wa, ba, adj, out);
}

// Round 10
// 10.128 us; speedup vs baseline: 1.3236x; 1.3236x over previous
//
#include <hip/hip_runtime.h>

#define NODE 512
#define DIM 64
#define BATCH 4

typedef __attribute__((ext_vector_type(8))) short bf16x8;   // 8 bf16 = 4 VGPRs
typedef __attribute__((ext_vector_type(4))) float f32x4;

#define LSTRIDE 520   // ushorts per LDS feat row: 1040B = 65*16B -> b128-aligned;
                      // read slot = fr*65 + jb/8 -> distinct mod 8 across fr

__device__ __forceinline__ unsigned short f2bf(float f) {   // RNE float->bf16
    unsigned int u = __float_as_uint(f);
    u += 0x7FFF + ((u >> 16) & 1);
    return (unsigned short)(u >> 16);
}

// R6 structure (best measured: 9.90us), single change: VMEM issue order.
// x loads (pre-barrier critical path) issue FIRST; wa/ba as float4 (was 16
// scalar loads); adj prefetch LAST (consumed only after the barrier, hides
// under phase 1). Geometry: grid 256 x 512thr = 1 block/CU, block = (b, 32-row
// i-group, 16-col d-group), 48.5KB LDS.
// Phase 1: feat table (512j x 16d) once into LDS, 2 j per thread, packed
//   ds_write_b32. f=softplus(x*(w0/sqrt2)+b0), E=exp(f*wa+ba), W=E*f
//   (|s|<~35: fp32-safe; exact softmax ratio -- masked terms exp(-1e9)=0).
// Phase 2: masked GEMM, wave (itl,kq): A-frag = adj 1/0 bf16 from prefetched
//   regs, B via ds_read_b128, 8 MFMAs; LDS-reduce; divide; store.
// A/B frags share slot->k map (kg*8+t) so HW k-permutation cancels.
// C/D map col=lane&15, row=(lane>>4)*4+reg (verified R3-R8).
__global__ __launch_bounds__(512) void k_fused6(const float* __restrict__ x,
                                                const float* __restrict__ w0,
                                                const float* __restrict__ b0,
                                                const float* __restrict__ wa,
                                                const float* __restrict__ ba,
                                                const int* __restrict__ adj,
                                                float* __restrict__ out) {
    __shared__ unsigned short Ep[16][LSTRIDE];   // 16.25 KiB
    __shared__ unsigned short Wp[16][LSTRIDE];   // 16.25 KiB
    __shared__ f32x4 red[2][4][2][64];           // 16 KiB

    const int blk = blockIdx.x;                  // 256 = 4b * 16itg * 4dt
    const int dt  = blk & 3;
    const int itg = (blk >> 2) & 15;
    const int b   = blk >> 6;
    const int tid = threadIdx.x;
    const int i0  = itg * 32;
    const int d0  = dt * 16;

    const int lane = tid & 63;
    const int w    = tid >> 6;       // 8 waves
    const int itl  = w & 1;
    const int kq   = w >> 1;         // K-chunk (128 j)
    const int fr   = lane & 15;
    const int kg   = lane >> 4;

    // ---- (1) x loads: the pre-barrier critical path, issue first ----
    // task A = tid, task B = 512+tid -> same d-quad dg, j-pairs jpA / jpA+128
    const int dg  = tid & 3;
    const int jpA = tid >> 2;
    const int jpB = jpA + 128;
    const float* pxA = x + ((size_t)(b * NODE + 2 * jpA) * DIM) + d0 + dg * 4;
    const float* pxB = x + ((size_t)(b * NODE + 2 * jpB) * DIM) + d0 + dg * 4;
    const float4 xA0 = *(const float4*)pxA;
    const float4 xA1 = *(const float4*)(pxA + DIM);
    const float4 xB0 = *(const float4*)pxB;
    const float4 xB1 = *(const float4*)(pxB + DIM);

    // ---- (2) params: also pre-barrier ----
    const float4 wa4 = *(const float4*)(wa + d0 + dg * 4);
    const float4 ba4 = *(const float4*)(ba + d0 + dg * 4);
    const float c  = 0.7071067811865476f * w0[0];
    const float bb = b0[0];

    // ---- (3) adj prefetch: consumed after barrier, issue last ----
    const int* pAdj = adj + (i0 + itl * 16 + fr) * NODE + kq * 128 + kg * 8;
    int4 pa0[4], pa1[4];
    #pragma unroll
    for (int m = 0; m < 4; ++m) {
        pa0[m] = *(const int4*)(pAdj + m * 32);
        pa1[m] = *(const int4*)(pAdj + m * 32 + 4);
    }

    // ---- Phase 1: feat math + packed LDS writes ----
    #pragma unroll
    for (int hh = 0; hh < 2; ++hh) {
        const int jp = hh ? jpB : jpA;
        const float4 v0 = hh ? xB0 : xA0;
        const float4 v1 = hh ? xB1 : xA1;
        #pragma unroll
        for (int i = 0; i < 4; ++i) {
            const int dl = dg * 4 + i;
            const float xv0 = (i == 0) ? v0.x : (i == 1) ? v0.y : (i == 2) ? v0.z : v0.w;
            const float xv1 = (i == 0) ? v1.x : (i == 1) ? v1.y : (i == 2) ? v1.z : v1.w;
            const float wad = (i == 0) ? wa4.x : (i == 1) ? wa4.y : (i == 2) ? wa4.z : wa4.w;
            const float bad = (i == 0) ? ba4.x : (i == 1) ? ba4.y : (i == 2) ? ba4.z : ba4.w;
            float z0 = fmaf(xv0, c, bb), z1 = fmaf(xv1, c, bb);
            float f0 = fmaxf(z0, 0.f) + __logf(1.f + __expf(-fabsf(z0)));
            float f1 = fmaxf(z1, 0.f) + __logf(1.f + __expf(-fabsf(z1)));
            float e0 = __expf(fmaf(f0, wad, bad));
            float e1 = __expf(fmaf(f1, wad, bad));
            unsigned int epk = (unsigned int)f2bf(e0) | ((unsigned int)f2bf(e1) << 16);
            unsigned int wpk = (unsigned int)f2bf(e0 * f0) | ((unsigned int)f2bf(e1 * f1) << 16);
            *(unsigned int*)&Ep[dl][2 * jp] = epk;
            *(unsigned int*)&Wp[dl][2 * jp] = wpk;
        }
    }
    __syncthreads();

    // ---- Phase 2: masked GEMM ----
    const int jb0 = kq * 128 + kg * 8;
    f32x4 accD = {0.f, 0.f, 0.f, 0.f};
    f32x4 accN = {0.f, 0.f, 0.f, 0.f};
    #pragma unroll
    for (int m = 0; m < 4; ++m) {
        union { bf16x8 v; unsigned short s[8]; } A;
        A.s[0] = pa0[m].x ? 0x3F80 : 0;  A.s[1] = pa0[m].y ? 0x3F80 : 0;
        A.s[2] = pa0[m].z ? 0x3F80 : 0;  A.s[3] = pa0[m].w ? 0x3F80 : 0;
        A.s[4] = pa1[m].x ? 0x3F80 : 0;  A.s[5] = pa1[m].y ? 0x3F80 : 0;
        A.s[6] = pa1[m].z ? 0x3F80 : 0;  A.s[7] = pa1[m].w ? 0x3F80 : 0;
        const int jb = jb0 + m * 32;
        bf16x8 BD = *(const bf16x8*)&Ep[fr][jb];
        bf16x8 BN = *(const bf16x8*)&Wp[fr][jb];
        accD = __builtin_amdgcn_mfma_f32_16x16x32_bf16(A.v, BD, accD, 0, 0, 0);
        accN = __builtin_amdgcn_mfma_f32_16x16x32_bf16(A.v, BN, accN, 0, 0, 0);
    }

    red[itl][kq][0][lane] = accD;
    red[itl][kq][1][lane] = accN;
    __syncthreads();

    if (w < 2) {
        const int t = w;
        f32x4 D = red[t][0][0][lane] + red[t][1][0][lane] + red[t][2][0][lane] + red[t][3][0][lane];
        f32x4 N = red[t][0][1][lane] + red[t][1][1][lane] + red[t][2][1][lane] + red[t][3][1][lane];
        #pragma unroll
        for (int r = 0; r < 4; ++r) {
            float dd = D[r], nn = N[r];
            float o = (dd != 0.f) ? nn / dd : 0.f;   // all-zero adj rows: P~2^-512
            out[((b * NODE) + i0 + t * 16 + kg * 4 + r) * DIM + d0 + fr] = o;
        }
    }
}

extern "C" void kernel_launch(void* const* d_in, const int* in_sizes, int n_in,
                              void* d_out, int out_size, void* d_ws, size_t ws_size,
                              hipStream_t stream) {
    const float* x  = (const float*)d_in[0];
    const float* w0 = (const float*)d_in[1];
    const float* b0 = (const float*)d_in[2];
    const float* wa = (const float*)d_in[3];
    const float* ba = (const float*)d_in[4];
    const int*  adj = (const int*)d_in[5];
    float* out = (float*)d_out;

    k_fused6<<<dim3(256), dim3(512), 0, stream>>>(x, w0, b0, wa, ba, adj, out);
}